// Round 3
// baseline (1155.721 us; speedup 1.0000x reference)
//
#include <hip/hip_runtime.h>
#include <stdint.h>

#define N_TOK 4096
#define TD 384
#define KNB 64
#define PD 128
#define HD 256
#define NPROJ 256  // 2*PD
#define RPB 32     // rows per block in pair kernel (divides KNB)

// ---- workspace layout (bytes) ----
// [0, 64)        int flags[16]: 0=mask bool-mode, 1=slot bool-mode,
//                               2=x dtype (0=f32,1=bf16), 3=pair_rep dtype
// [64, ...)      canonical f32 weights, float offsets below
// [1<<20, ...)   proj  f32 [N_TOK][NPROJ]   (4 MB)
#define CAN_LN_G 0
#define CAN_LN_B 384
#define CAN_WX   768
#define CAN_T_G  99072
#define CAN_T_B  99200
#define CAN_W1   99328
#define CAN_B1   132096
#define CAN_W2   132352
#define CAN_B2   165120
#define CAN_TOTAL 165248

static __device__ __forceinline__ float bf2f(unsigned short u) {
    return __uint_as_float(((unsigned int)u) << 16);
}
// dual-dtype float load: mode 1 = bf16 stream, mode 0 = f32 stream
static __device__ __forceinline__ float loadf(const void* p, int mode, int i) {
    return mode ? bf2f(((const unsigned short*)p)[i]) : ((const float*)p)[i];
}
// Bool-buffer storage modes: 0=int32, 1=byte, 2=bf16, 3=f32
static __device__ __forceinline__ bool load_flag(const void* p, int mode, int i) {
    if (mode == 0) return ((const int*)p)[i] != 0;
    if (mode == 1) return ((const unsigned char*)p)[i] != 0;
    if (mode == 2) return ((const unsigned short*)p)[i] != 0;
    return ((const unsigned int*)p)[i] != 0;
}

static __device__ __forceinline__ bool plaus16(unsigned int h) {
    if (h == 0u) return true;
    unsigned int e = (h >> 7) & 0xFFu;
    return (e >= 0x60u && e <= 0x9Fu);
}

// One block, 256 threads = 4 waves.
// wave0: dtype of x -> flags[2]; wave1: dtype of pair_rep -> flags[3]
// wave2: bool mode of mask -> flags[0]; wave3: bool mode of slot -> flags[1]
__global__ __launch_bounds__(256) void detect_kernel(
        const void* __restrict__ x, const void* __restrict__ pair_rep,
        const void* __restrict__ mask, const void* __restrict__ slot,
        int* __restrict__ flags) {
    const int t = threadIdx.x;
    const int wave = t >> 6, lane = t & 63;
    if (wave < 2) {
        const unsigned int* w = (const unsigned int*)(wave == 0 ? x : pair_rep);
        unsigned int v = w[lane];
        bool pl = plaus16(v & 0xFFFFu) && plaus16(v >> 16);
        unsigned long long b = __ballot(pl);
        if (lane == 0) flags[2 + wave] = (__popcll(b) >= 56) ? 1 : 0;
    } else {
        const unsigned int* w = (const unsigned int*)(wave == 2 ? mask : slot);
        bool ok01 = true, okbf = true, anybf_lo = false;
        #pragma unroll
        for (int j = 0; j < 4; ++j) {
            unsigned int v = w[lane * 4 + j];
            if (v > 1u) ok01 = false;
            unsigned int h0 = v & 0xFFFFu, h1 = v >> 16;
            if (!(h0 == 0u || h0 == 0x3F80u)) okbf = false;
            if (!(h1 == 0u || h1 == 0x3F80u)) okbf = false;
            if (h0 == 0x3F80u) anybf_lo = true;
        }
        unsigned long long b01 = __ballot(ok01);
        unsigned long long bbf = __ballot(okbf);
        unsigned long long bev = __ballot(anybf_lo);
        if (lane == 0) {
            int mode;
            if (b01 == ~0ull) mode = 0;
            else if (bbf == ~0ull) mode = (bev != 0ull) ? 2 : 3;
            else mode = 1;
            flags[wave - 2] = mode;
        }
    }
}

// Convert the 9 small weight tensors into canonical f32 in ws.
__global__ __launch_bounds__(256) void canon_kernel(
        const void* p0, const void* p1, const void* p2, const void* p3,
        const void* p4, const void* p5, const void* p6, const void* p7,
        const void* p8, const int* __restrict__ flags,
        float* __restrict__ dst) {
    const int offs[9]   = {CAN_LN_G, CAN_LN_B, CAN_WX, CAN_T_G, CAN_T_B,
                           CAN_W1, CAN_B1, CAN_W2, CAN_B2};
    const int mode = flags[2];  // weights share x's dtype (uniform conversion)
    int e = blockIdx.x * 256 + threadIdx.x;
    if (e >= CAN_TOTAL) return;
    int s = 0;
    #pragma unroll
    for (int i = 1; i < 9; ++i) if (e >= offs[i]) s = i;
    const int local = e - offs[s];
    const void* p = (s == 0) ? p0 : (s == 1) ? p1 : (s == 2) ? p2 :
                    (s == 3) ? p3 : (s == 4) ? p4 : (s == 5) ? p5 :
                    (s == 6) ? p6 : (s == 7) ? p7 : p8;
    dst[e] = loadf(p, mode, local);
}

// Per-token layernorm over TD=384 then proj = ln @ Wx (TD x 256).
// One block per token; thread c computes output column c.
__global__ __launch_bounds__(256) void ln_proj_kernel(
        const void* __restrict__ x,
        const float* __restrict__ canon,
        const int* __restrict__ flags,
        float* __restrict__ proj) {
    __shared__ float xs[TD];
    __shared__ float red[8];
    const int n = blockIdx.x;
    const int t = threadIdx.x;
    const int wave = t >> 6, lane = t & 63;
    const int xm = flags[2];

    float v0 = 0.f, v1 = 0.f;
    v0 = loadf(x, xm, n * TD + t);
    if (t + 256 < TD) v1 = loadf(x, xm, n * TD + t + 256);
    float s = v0 + v1, sq = v0 * v0 + v1 * v1;
    #pragma unroll
    for (int off = 32; off > 0; off >>= 1) {
        s += __shfl_down(s, off);
        sq += __shfl_down(sq, off);
    }
    if (lane == 0) { red[wave] = s; red[4 + wave] = sq; }
    __syncthreads();
    const float sum = red[0] + red[1] + red[2] + red[3];
    const float sumsq = red[4] + red[5] + red[6] + red[7];
    const float mu = sum * (1.f / TD);
    const float var = sumsq * (1.f / TD) - mu * mu;
    const float rs = rsqrtf(var + 1e-5f);
    const float* lng = canon + CAN_LN_G;
    const float* lnb = canon + CAN_LN_B;
    xs[t] = (v0 - mu) * rs * lng[t] + lnb[t];
    if (t + 256 < TD)
        xs[t + 256] = (v1 - mu) * rs * lng[t + 256] + lnb[t + 256];
    __syncthreads();

    // proj[n][c] = sum_i xs[i] * Wx[i][c]
    const int c = t;
    float acc = 0.f;
    const float* wc = canon + CAN_WX + c;
    #pragma unroll 4
    for (int i = 0; i < TD; ++i)
        acc += xs[i] * wc[i * NPROJ];
    proj[n * NPROJ + c] = acc;
}

// Fused pair update + transition.
// Block handles RPB=32 consecutive (n,k) rows (all sharing one n).
__global__ __launch_bounds__(256) void pair_kernel(
        const void* __restrict__ pair_rep,
        const void* __restrict__ mask,
        const int* __restrict__ nbr,
        const void* __restrict__ slot,
        const float* __restrict__ canon,
        const float* __restrict__ proj,
        const int* __restrict__ flags,
        float* __restrict__ out) {
    __shared__ float zraw[RPB][PD];      // 16 KB, masked z, kept for residual
    __shared__ float big[RPB * HD];      // 32 KB, zn (as [r*PD+i]) then H (as [r*HD+c])
    __shared__ float xp2s[PD];
    __shared__ float pmf[RPB];
    __shared__ int   idxs[RPB];

    const int t = threadIdx.x;
    const int row0 = blockIdx.x * RPB;
    const int n = row0 >> 6;           // row = n*KNB + k, RPB divides KNB
    const int k0 = row0 & (KNB - 1);
    const int mmode = flags[0], smode = flags[1], prm = flags[3];

    // Phase 1: per-block metadata
    if (t < PD) xp2s[t] = proj[n * NPROJ + PD + t];
    if (t < RPB) {
        const bool mask_n = load_flag(mask, mmode, n);
        const int kk = k0 + t;
        const int idx = nbr[n * KNB + kk];
        idxs[t] = idx;
        const bool pm = mask_n && load_flag(mask, mmode, idx) &&
                        load_flag(slot, smode, n * KNB + kk);
        pmf[t] = pm ? 1.f : 0.f;
    }
    __syncthreads();

    // Phase 2: assemble z = (pair_rep + xp2 + xp1[idx]) * pm
    #pragma unroll
    for (int j = 0; j < (RPB * PD) / 256; ++j) {
        const int f = t + 256 * j;
        const int k = f >> 7, p = f & (PD - 1);
        const int row = row0 + k;
        float z = loadf(pair_rep, prm, row * PD + p) + xp2s[p]
                  + proj[idxs[k] * NPROJ + p];
        z *= pmf[k];
        zraw[k][p] = z;
    }
    __syncthreads();

    // Phase 3: per-row LN over P=128 (wave per 8 rows, shuffle reduce)
    {
        const int wave = t >> 6, lane = t & 63;
        const float g0 = canon[CAN_T_G + lane], g1 = canon[CAN_T_G + lane + 64];
        const float bb0 = canon[CAN_T_B + lane], bb1v = canon[CAN_T_B + lane + 64];
        #pragma unroll
        for (int rr = 0; rr < RPB / 4; ++rr) {
            const int r = wave * (RPB / 4) + rr;
            const float a0 = zraw[r][lane], a1 = zraw[r][lane + 64];
            float s = a0 + a1, sq = a0 * a0 + a1 * a1;
            #pragma unroll
            for (int off = 32; off > 0; off >>= 1) {
                s += __shfl_down(s, off);
                sq += __shfl_down(sq, off);
            }
            s = __shfl(s, 0); sq = __shfl(sq, 0);
            const float mu = s * (1.f / PD);
            const float var = sq * (1.f / PD) - mu * mu;
            const float rs = rsqrtf(var + 1e-5f);
            big[r * PD + lane]      = (a0 - mu) * rs * g0 + bb0;
            big[r * PD + lane + 64] = (a1 - mu) * rs * g1 + bb1v;
        }
    }
    __syncthreads();

    // Phase 4: H = relu(zn @ W1 + b1); thread c owns column c for all 32 rows
    {
        const int c = t;
        float acc[RPB];
        #pragma unroll
        for (int r = 0; r < RPB; ++r) acc[r] = 0.f;
        const float* W1f = canon + CAN_W1;
        for (int i = 0; i < PD; i += 4) {
            const float w0 = W1f[(i + 0) * HD + c];
            const float w1 = W1f[(i + 1) * HD + c];
            const float w2 = W1f[(i + 2) * HD + c];
            const float w3 = W1f[(i + 3) * HD + c];
            #pragma unroll
            for (int r = 0; r < RPB; ++r) {
                const float4 zv = *(const float4*)&big[r * PD + i];
                acc[r] += zv.x * w0 + zv.y * w1 + zv.z * w2 + zv.w * w3;
            }
        }
        const float bb = canon[CAN_B1 + c];
        __syncthreads();  // all zn reads complete before overwriting big with H
        #pragma unroll
        for (int r = 0; r < RPB; ++r) {
            const float h = acc[r] + bb;
            big[r * HD + c] = h > 0.f ? h : 0.f;
        }
    }
    __syncthreads();

    // Phase 5: O = H @ W2 + b2; out = z + pm*O.
    // Thread t: column p = t&127, row half rh = t>>7 (16 rows each).
    {
        const int p = t & (PD - 1);
        const int rh = t >> 7;
        float oacc[16];
        #pragma unroll
        for (int r = 0; r < 16; ++r) oacc[r] = 0.f;
        const float* W2f = canon + CAN_W2;
        for (int cc = 0; cc < HD; cc += 4) {
            const float w0 = W2f[(cc + 0) * PD + p];
            const float w1 = W2f[(cc + 1) * PD + p];
            const float w2 = W2f[(cc + 2) * PD + p];
            const float w3 = W2f[(cc + 3) * PD + p];
            #pragma unroll
            for (int r = 0; r < 16; ++r) {
                const int rr = rh * 16 + r;
                const float4 hv = *(const float4*)&big[rr * HD + cc];
                oacc[r] += hv.x * w0 + hv.y * w1 + hv.z * w2 + hv.w * w3;
            }
        }
        const float bb = canon[CAN_B2 + p];
        #pragma unroll
        for (int r = 0; r < 16; ++r) {
            const int rr = rh * 16 + r;
            const float o = (oacc[r] + bb) * pmf[rr];
            // OUTPUT IS FLOAT32 (reference dtype) — this was the round-2 bug.
            out[(row0 + rr) * PD + p] = zraw[rr][p] + o;
        }
    }
}

extern "C" void kernel_launch(void* const* d_in, const int* in_sizes, int n_in,
                              void* d_out, int out_size, void* d_ws, size_t ws_size,
                              hipStream_t stream) {
    const void* x        = d_in[0];
    const void* pair_rep = d_in[1];
    const void* mask     = d_in[2];
    const int*  nbr      = (const int*)d_in[3];
    const void* slot     = d_in[4];
    float* out = (float*)d_out;

    int*   flags = (int*)d_ws;
    float* canon = (float*)((char*)d_ws + 64);
    float* proj  = (float*)((char*)d_ws + (1 << 20));  // 4 MB f32

    detect_kernel<<<1, 256, 0, stream>>>(x, pair_rep, mask, slot, flags);
    canon_kernel<<<(CAN_TOTAL + 255) / 256, 256, 0, stream>>>(
        d_in[5], d_in[6], d_in[7], d_in[8], d_in[9], d_in[10], d_in[11],
        d_in[12], d_in[13], flags, canon);
    ln_proj_kernel<<<N_TOK, 256, 0, stream>>>(x, canon, flags, proj);
    pair_kernel<<<(N_TOK * KNB) / RPB, 256, 0, stream>>>(
        pair_rep, mask, nbr, slot, canon, proj, flags, out);
}

// Round 4
// 511.595 us; speedup vs baseline: 2.2591x; 2.2591x over previous
//
#include <hip/hip_runtime.h>
#include <stdint.h>

#define N_TOK 4096
#define TD 384
#define KNB 64
#define PD 128
#define HD 256
#define NPROJ 256  // 2*PD
#define RPB 32     // rows per block in pair kernel (divides KNB)
#define TPB_LN 16  // tokens per block in ln kernel

// ---- workspace layout (bytes) ----
// [0, 64)            int flags[16]
// [64, 661056)       canonical f32 weights (float offsets below)
// [663552, 991232)   bf16 transposed weights (short offsets below)
// [1<<20, 1<<20+4MB) proj f32 [N_TOK][NPROJ]
#define CAN_LN_G 0
#define CAN_LN_B 384
#define CAN_WX   768
#define CAN_T_G  99072
#define CAN_T_B  99200
#define CAN_W1   99328
#define CAN_B1   132096
#define CAN_W2   132352
#define CAN_B2   165120
#define CAN_TOTAL 165248

#define BW_OFF   663552   // byte offset of bf16 region (16B aligned)
#define WXT_OFF  0        // short index: WxT [256][384]
#define W1T_OFF  98304    // short index: W1T [256][128]
#define W2T_OFF  131072   // short index: W2T [128][256]
#define BW_TOTAL 163840
#define PROJ_OFF (1 << 20)

typedef __attribute__((ext_vector_type(8))) short bf16x8;
typedef __attribute__((ext_vector_type(4))) float f32x4;

static __device__ __forceinline__ float bf2f(unsigned short u) {
    return __uint_as_float(((unsigned int)u) << 16);
}
static __device__ __forceinline__ unsigned short f2bf(float f) {
    unsigned int x = __float_as_uint(f);
    return (unsigned short)((x + 0x7FFFu + ((x >> 16) & 1u)) >> 16);
}
// dual-dtype float load: mode 1 = bf16 stream, mode 0 = f32 stream
static __device__ __forceinline__ float loadf(const void* p, int mode, int i) {
    return mode ? bf2f(((const unsigned short*)p)[i]) : ((const float*)p)[i];
}
// Bool-buffer storage modes: 0=int32, 1=byte, 2=bf16, 3=f32
static __device__ __forceinline__ bool load_flag(const void* p, int mode, int i) {
    if (mode == 0) return ((const int*)p)[i] != 0;
    if (mode == 1) return ((const unsigned char*)p)[i] != 0;
    if (mode == 2) return ((const unsigned short*)p)[i] != 0;
    return ((const unsigned int*)p)[i] != 0;
}
static __device__ __forceinline__ bool plaus16(unsigned int h) {
    if (h == 0u) return true;
    unsigned int e = (h >> 7) & 0xFFu;
    return (e >= 0x60u && e <= 0x9Fu);
}

__global__ __launch_bounds__(256) void detect_kernel(
        const void* __restrict__ x, const void* __restrict__ pair_rep,
        const void* __restrict__ mask, const void* __restrict__ slot,
        int* __restrict__ flags) {
    const int t = threadIdx.x;
    const int wave = t >> 6, lane = t & 63;
    if (wave < 2) {
        const unsigned int* w = (const unsigned int*)(wave == 0 ? x : pair_rep);
        unsigned int v = w[lane];
        bool pl = plaus16(v & 0xFFFFu) && plaus16(v >> 16);
        unsigned long long b = __ballot(pl);
        if (lane == 0) flags[2 + wave] = (__popcll(b) >= 56) ? 1 : 0;
    } else {
        const unsigned int* w = (const unsigned int*)(wave == 2 ? mask : slot);
        bool ok01 = true, okbf = true, anybf_lo = false;
        #pragma unroll
        for (int j = 0; j < 4; ++j) {
            unsigned int v = w[lane * 4 + j];
            if (v > 1u) ok01 = false;
            unsigned int h0 = v & 0xFFFFu, h1 = v >> 16;
            if (!(h0 == 0u || h0 == 0x3F80u)) okbf = false;
            if (!(h1 == 0u || h1 == 0x3F80u)) okbf = false;
            if (h0 == 0x3F80u) anybf_lo = true;
        }
        unsigned long long b01 = __ballot(ok01);
        unsigned long long bbf = __ballot(okbf);
        unsigned long long bev = __ballot(anybf_lo);
        if (lane == 0) {
            int mode;
            if (b01 == ~0ull) mode = 0;
            else if (bbf == ~0ull) mode = (bev != 0ull) ? 2 : 3;
            else mode = 1;
            flags[wave - 2] = mode;
        }
    }
}

// Canonical f32 copies of the 9 small weight tensors.
__global__ __launch_bounds__(256) void canon_kernel(
        const void* p0, const void* p1, const void* p2, const void* p3,
        const void* p4, const void* p5, const void* p6, const void* p7,
        const void* p8, const int* __restrict__ flags,
        float* __restrict__ dst) {
    const int offs[9] = {CAN_LN_G, CAN_LN_B, CAN_WX, CAN_T_G, CAN_T_B,
                         CAN_W1, CAN_B1, CAN_W2, CAN_B2};
    const int mode = flags[2];
    int e = blockIdx.x * 256 + threadIdx.x;
    if (e >= CAN_TOTAL) return;
    int s = 0;
    #pragma unroll
    for (int i = 1; i < 9; ++i) if (e >= offs[i]) s = i;
    const int local = e - offs[s];
    const void* p = (s == 0) ? p0 : (s == 1) ? p1 : (s == 2) ? p2 :
                    (s == 3) ? p3 : (s == 4) ? p4 : (s == 5) ? p5 :
                    (s == 6) ? p6 : (s == 7) ? p7 : p8;
    dst[e] = loadf(p, mode, local);
}

// bf16 transposed weights: lane n holds contiguous K -> B-operand fragments.
__global__ __launch_bounds__(256) void canon2_kernel(
        const void* __restrict__ Wx, const void* __restrict__ W1,
        const void* __restrict__ W2, const int* __restrict__ flags,
        short* __restrict__ dst) {
    const int mode = flags[2];
    int e = blockIdx.x * 256 + threadIdx.x;
    if (e >= BW_TOTAL) return;
    int src; const void* p;
    if (e < W1T_OFF)      { int n = e / TD, k = e - n * TD;       p = Wx; src = k * NPROJ + n; }
    else if (e < W2T_OFF) { int l = e - W1T_OFF; int n = l >> 7, k = l & 127; p = W1; src = k * HD + n; }
    else                  { int l = e - W2T_OFF; int n = l >> 8, k = l & 255; p = W2; src = k * PD + n; }
    dst[e] = (short)f2bf(loadf(p, mode, src));
}

// LN over TD=384 for 16 tokens, then proj = xn @ Wx via MFMA (K=384).
__global__ __launch_bounds__(256) void ln_proj_mfma(
        const void* __restrict__ x,
        const float* __restrict__ canon,
        const short* __restrict__ wxt,
        const int* __restrict__ flags,
        float* __restrict__ proj) {
    __shared__ short xnb[TPB_LN][TD + 8];   // +8 pad: stride 196 words == 4 mod 32
    const int t = threadIdx.x, wv = t >> 6, lane = t & 63;
    const int tok0 = blockIdx.x * TPB_LN;
    const int xm = flags[2];

    float g[6], bv[6];
    #pragma unroll
    for (int j = 0; j < 6; ++j) {
        g[j]  = canon[CAN_LN_G + lane + 64 * j];
        bv[j] = canon[CAN_LN_B + lane + 64 * j];
    }
    #pragma unroll
    for (int rr = 0; rr < TPB_LN / 4; ++rr) {
        const int r = wv * (TPB_LN / 4) + rr;
        float v[6], s = 0.f, sq = 0.f;
        #pragma unroll
        for (int j = 0; j < 6; ++j) {
            v[j] = loadf(x, xm, (tok0 + r) * TD + lane + 64 * j);
            s += v[j]; sq += v[j] * v[j];
        }
        #pragma unroll
        for (int off = 32; off > 0; off >>= 1) {
            s += __shfl_down(s, off); sq += __shfl_down(sq, off);
        }
        s = __shfl(s, 0); sq = __shfl(sq, 0);
        const float mu = s * (1.f / TD);
        const float var = sq * (1.f / TD) - mu * mu;
        const float rs = rsqrtf(var + 1e-5f);
        #pragma unroll
        for (int j = 0; j < 6; ++j)
            xnb[r][lane + 64 * j] = (short)f2bf((v[j] - mu) * rs * g[j] + bv[j]);
    }
    __syncthreads();

    const int qr = lane >> 4, ln16 = lane & 15;
    const int n0 = wv * 64;
    f32x4 acc[4];
    #pragma unroll
    for (int nt = 0; nt < 4; ++nt) acc[nt] = f32x4{0.f, 0.f, 0.f, 0.f};
    #pragma unroll
    for (int ks = 0; ks < 12; ++ks) {
        const int k0 = ks * 32 + qr * 8;
        bf16x8 a = *(const bf16x8*)&xnb[ln16][k0];
        #pragma unroll
        for (int nt = 0; nt < 4; ++nt) {
            bf16x8 b = *(const bf16x8*)(wxt + (n0 + nt * 16 + ln16) * TD + k0);
            acc[nt] = __builtin_amdgcn_mfma_f32_16x16x32_bf16(a, b, acc[nt], 0, 0, 0);
        }
    }
    #pragma unroll
    for (int nt = 0; nt < 4; ++nt) {
        const int c = n0 + nt * 16 + ln16;
        #pragma unroll
        for (int r = 0; r < 4; ++r)
            proj[(tok0 + qr * 4 + r) * NPROJ + c] = acc[nt][r];
    }
}

// Fused pair update + transition, MFMA edition. 32 rows/block (one n).
__global__ __launch_bounds__(256, 3) void pair_kernel(
        const void* __restrict__ pair_rep,
        const void* __restrict__ mask,
        const int* __restrict__ nbr,
        const void* __restrict__ slot,
        const float* __restrict__ canon,
        const short* __restrict__ w1t,
        const short* __restrict__ w2t,
        const float* __restrict__ proj,
        const int* __restrict__ flags,
        float* __restrict__ out) {
    __shared__ float zraw[RPB][PD];         // 16 KB, masked z (residual)
    __shared__ short znb[RPB][PD + 8];      // 8.5 KB, LN(z) bf16, pad->2-way banks
    __shared__ short Hb[RPB][HD + 8];       // 16.5 KB, relu hidden bf16
    __shared__ float xp2s[PD];
    __shared__ float pmf[RPB];
    __shared__ int   idxs[RPB];

    const int t = threadIdx.x;
    const int wv = t >> 6, lane = t & 63;
    const int qr = lane >> 4, ln16 = lane & 15;
    const int row0 = blockIdx.x * RPB;
    const int n = row0 >> 6;
    const int k0blk = row0 & (KNB - 1);
    const int mmode = flags[0], smode = flags[1], prm = flags[3];

    // Phase 1: metadata
    if (t < PD) xp2s[t] = proj[n * NPROJ + PD + t];
    if (t < RPB) {
        const bool mask_n = load_flag(mask, mmode, n);
        const int kk = k0blk + t;
        const int idx = nbr[n * KNB + kk];
        idxs[t] = idx;
        const bool pm = mask_n && load_flag(mask, mmode, idx) &&
                        load_flag(slot, smode, n * KNB + kk);
        pmf[t] = pm ? 1.f : 0.f;
    }
    __syncthreads();

    // Phase 2: z = (pair_rep + xp2 + xp1[idx]) * pm
    #pragma unroll
    for (int j = 0; j < (RPB * PD) / 256; ++j) {
        const int f = t + 256 * j;
        const int k = f >> 7, p = f & (PD - 1);
        float z = loadf(pair_rep, prm, (row0 + k) * PD + p) + xp2s[p]
                  + proj[idxs[k] * NPROJ + p];
        zraw[k][p] = z * pmf[k];
    }
    __syncthreads();

    // Phase 3: per-row LN -> znb (bf16)
    {
        const float g0 = canon[CAN_T_G + lane], g1 = canon[CAN_T_G + lane + 64];
        const float bb0 = canon[CAN_T_B + lane], bb1 = canon[CAN_T_B + lane + 64];
        #pragma unroll
        for (int rr = 0; rr < RPB / 4; ++rr) {
            const int r = wv * (RPB / 4) + rr;
            const float a0 = zraw[r][lane], a1 = zraw[r][lane + 64];
            float s = a0 + a1, sq = a0 * a0 + a1 * a1;
            #pragma unroll
            for (int off = 32; off > 0; off >>= 1) {
                s += __shfl_down(s, off); sq += __shfl_down(sq, off);
            }
            s = __shfl(s, 0); sq = __shfl(sq, 0);
            const float mu = s * (1.f / PD);
            const float var = sq * (1.f / PD) - mu * mu;
            const float rs = rsqrtf(var + 1e-5f);
            znb[r][lane]      = (short)f2bf((a0 - mu) * rs * g0 + bb0);
            znb[r][lane + 64] = (short)f2bf((a1 - mu) * rs * g1 + bb1);
        }
    }
    __syncthreads();

    // Phase 4: H = relu(zn @ W1 + b1), MFMA 16x16x32. Wave owns 64 H-cols.
    {
        const int n0 = wv * 64;
        f32x4 acc1[2][4];
        #pragma unroll
        for (int mt = 0; mt < 2; ++mt)
            #pragma unroll
            for (int nt = 0; nt < 4; ++nt) acc1[mt][nt] = f32x4{0.f, 0.f, 0.f, 0.f};
        #pragma unroll
        for (int ks = 0; ks < 4; ++ks) {
            const int k0 = ks * 32 + qr * 8;
            bf16x8 a0 = *(const bf16x8*)&znb[ln16][k0];
            bf16x8 a1 = *(const bf16x8*)&znb[16 + ln16][k0];
            #pragma unroll
            for (int nt = 0; nt < 4; ++nt) {
                bf16x8 b = *(const bf16x8*)(w1t + (n0 + nt * 16 + ln16) * PD + k0);
                acc1[0][nt] = __builtin_amdgcn_mfma_f32_16x16x32_bf16(a0, b, acc1[0][nt], 0, 0, 0);
                acc1[1][nt] = __builtin_amdgcn_mfma_f32_16x16x32_bf16(a1, b, acc1[1][nt], 0, 0, 0);
            }
        }
        #pragma unroll
        for (int nt = 0; nt < 4; ++nt) {
            const int c = n0 + nt * 16 + ln16;
            const float bb = canon[CAN_B1 + c];
            #pragma unroll
            for (int mt = 0; mt < 2; ++mt)
                #pragma unroll
                for (int r = 0; r < 4; ++r) {
                    const float h = acc1[mt][nt][r] + bb;
                    Hb[mt * 16 + qr * 4 + r][c] = (short)f2bf(h > 0.f ? h : 0.f);
                }
        }
    }
    __syncthreads();

    // Phase 5: O = H @ W2 + b2; out = z + pm*O. Wave owns 32 out-cols.
    {
        const int p0 = wv * 32;
        f32x4 acc2[2][2];
        #pragma unroll
        for (int mt = 0; mt < 2; ++mt)
            #pragma unroll
            for (int nt = 0; nt < 2; ++nt) acc2[mt][nt] = f32x4{0.f, 0.f, 0.f, 0.f};
        #pragma unroll
        for (int ks = 0; ks < 8; ++ks) {
            const int k0 = ks * 32 + qr * 8;
            bf16x8 a0 = *(const bf16x8*)&Hb[ln16][k0];
            bf16x8 a1 = *(const bf16x8*)&Hb[16 + ln16][k0];
            #pragma unroll
            for (int nt = 0; nt < 2; ++nt) {
                bf16x8 b = *(const bf16x8*)(w2t + (p0 + nt * 16 + ln16) * HD + k0);
                acc2[0][nt] = __builtin_amdgcn_mfma_f32_16x16x32_bf16(a0, b, acc2[0][nt], 0, 0, 0);
                acc2[1][nt] = __builtin_amdgcn_mfma_f32_16x16x32_bf16(a1, b, acc2[1][nt], 0, 0, 0);
            }
        }
        #pragma unroll
        for (int nt = 0; nt < 2; ++nt) {
            const int p = p0 + nt * 16 + ln16;
            const float bb = canon[CAN_B2 + p];
            #pragma unroll
            for (int mt = 0; mt < 2; ++mt)
                #pragma unroll
                for (int r = 0; r < 4; ++r) {
                    const int row = mt * 16 + qr * 4 + r;
                    const float o = (acc2[mt][nt][r] + bb) * pmf[row];
                    out[(row0 + row) * PD + p] = zraw[row][p] + o;
                }
        }
    }
}

extern "C" void kernel_launch(void* const* d_in, const int* in_sizes, int n_in,
                              void* d_out, int out_size, void* d_ws, size_t ws_size,
                              hipStream_t stream) {
    const void* x        = d_in[0];
    const void* pair_rep = d_in[1];
    const void* mask     = d_in[2];
    const int*  nbr      = (const int*)d_in[3];
    const void* slot     = d_in[4];
    float* out = (float*)d_out;

    int*   flags = (int*)d_ws;
    float* canon = (float*)((char*)d_ws + 64);
    short* bw    = (short*)((char*)d_ws + BW_OFF);
    const short* wxt = bw + WXT_OFF;
    const short* w1t = bw + W1T_OFF;
    const short* w2t = bw + W2T_OFF;
    float* proj  = (float*)((char*)d_ws + PROJ_OFF);

    detect_kernel<<<1, 256, 0, stream>>>(x, pair_rep, mask, slot, flags);
    canon_kernel<<<(CAN_TOTAL + 255) / 256, 256, 0, stream>>>(
        d_in[5], d_in[6], d_in[7], d_in[8], d_in[9], d_in[10], d_in[11],
        d_in[12], d_in[13], flags, canon);
    canon2_kernel<<<(BW_TOTAL + 255) / 256, 256, 0, stream>>>(
        d_in[7], d_in[10], d_in[12], flags, bw);
    ln_proj_mfma<<<N_TOK / TPB_LN, 256, 0, stream>>>(x, canon, wxt, flags, proj);
    pair_kernel<<<(N_TOK * KNB) / RPB, 256, 0, stream>>>(
        pair_rep, mask, nbr, slot, canon, w1t, w2t, proj, flags, out);
}

// Round 5
// 467.337 us; speedup vs baseline: 2.4730x; 1.0947x over previous
//
#include <hip/hip_runtime.h>
#include <stdint.h>

#define N_TOK 4096
#define TD 384
#define KNB 64
#define PD 128
#define HD 256
#define NPROJ 256  // 2*PD
#define RPB 32     // rows per tile
#define TPB_LN 16  // tokens per block in ln kernel
#define TILES_PER_BLK 8

// ---- workspace layout (bytes) ----
// [0,64) int flags[16]; [64,661056) f32 canon; [663552,991232) bf16 weights;
// [1<<20, +2MB) projb bf16 [4096][256]
#define CAN_LN_G 0
#define CAN_LN_B 384
#define CAN_WX   768
#define CAN_T_G  99072
#define CAN_T_B  99200
#define CAN_W1   99328
#define CAN_B1   132096
#define CAN_W2   132352
#define CAN_B2   165120
#define CAN_TOTAL 165248

#define BW_OFF   663552
#define WXT_OFF  0        // WxT [256][384]
#define W1T_OFF  98304    // W1T [256][128]
#define W2T_OFF  131072   // W2T [128][256]
#define BW_TOTAL 163840
#define PROJ_OFF (1 << 20)

typedef __attribute__((ext_vector_type(8))) short bf16x8;
typedef __attribute__((ext_vector_type(4))) float f32x4;

static __device__ __forceinline__ float bf2f(unsigned short u) {
    return __uint_as_float(((unsigned int)u) << 16);
}
static __device__ __forceinline__ unsigned short f2bf(float f) {
    unsigned int x = __float_as_uint(f);
    return (unsigned short)((x + 0x7FFFu + ((x >> 16) & 1u)) >> 16);
}
static __device__ __forceinline__ float loadf(const void* p, int mode, int i) {
    return mode ? bf2f(((const unsigned short*)p)[i]) : ((const float*)p)[i];
}
// raw word of a bool element (any storage mode); nonzero == true for all modes
static __device__ __forceinline__ unsigned int flag_word(const void* p, int mode, int i) {
    if (mode == 0) return ((const unsigned int*)p)[i];
    if (mode == 1) return (unsigned int)((const unsigned char*)p)[i];
    if (mode == 2) return (unsigned int)((const unsigned short*)p)[i];
    return ((const unsigned int*)p)[i];
}
static __device__ __forceinline__ bool plaus16(unsigned int h) {
    if (h == 0u) return true;
    unsigned int e = (h >> 7) & 0xFFu;
    return (e >= 0x60u && e <= 0x9Fu);
}

__global__ __launch_bounds__(256) void detect_kernel(
        const void* __restrict__ x, const void* __restrict__ pair_rep,
        const void* __restrict__ mask, const void* __restrict__ slot,
        int* __restrict__ flags) {
    const int t = threadIdx.x;
    const int wave = t >> 6, lane = t & 63;
    if (wave < 2) {
        const unsigned int* w = (const unsigned int*)(wave == 0 ? x : pair_rep);
        unsigned int v = w[lane];
        bool pl = plaus16(v & 0xFFFFu) && plaus16(v >> 16);
        unsigned long long b = __ballot(pl);
        if (lane == 0) flags[2 + wave] = (__popcll(b) >= 56) ? 1 : 0;
    } else {
        const unsigned int* w = (const unsigned int*)(wave == 2 ? mask : slot);
        bool ok01 = true, okbf = true, anybf_lo = false;
        #pragma unroll
        for (int j = 0; j < 4; ++j) {
            unsigned int v = w[lane * 4 + j];
            if (v > 1u) ok01 = false;
            unsigned int h0 = v & 0xFFFFu, h1 = v >> 16;
            if (!(h0 == 0u || h0 == 0x3F80u)) okbf = false;
            if (!(h1 == 0u || h1 == 0x3F80u)) okbf = false;
            if (h0 == 0x3F80u) anybf_lo = true;
        }
        unsigned long long b01 = __ballot(ok01);
        unsigned long long bbf = __ballot(okbf);
        unsigned long long bev = __ballot(anybf_lo);
        if (lane == 0) {
            int mode;
            if (b01 == ~0ull) mode = 0;
            else if (bbf == ~0ull) mode = (bev != 0ull) ? 2 : 3;
            else mode = 1;
            flags[wave - 2] = mode;
        }
    }
}

// f32 canon of 9 weight tensors + bf16 transposed Wx/W1/W2, one kernel.
__global__ __launch_bounds__(256) void prep_kernel(
        const void* p0, const void* p1, const void* p2, const void* p3,
        const void* p4, const void* p5, const void* p6, const void* p7,
        const void* p8, const int* __restrict__ flags,
        float* __restrict__ dstf, short* __restrict__ dstb) {
    const int mode = flags[2];
    int e = blockIdx.x * 256 + threadIdx.x;
    if (e < CAN_TOTAL) {
        const int offs[9] = {CAN_LN_G, CAN_LN_B, CAN_WX, CAN_T_G, CAN_T_B,
                             CAN_W1, CAN_B1, CAN_W2, CAN_B2};
        int s = 0;
        #pragma unroll
        for (int i = 1; i < 9; ++i) if (e >= offs[i]) s = i;
        const int local = e - offs[s];
        const void* p = (s == 0) ? p0 : (s == 1) ? p1 : (s == 2) ? p2 :
                        (s == 3) ? p3 : (s == 4) ? p4 : (s == 5) ? p5 :
                        (s == 6) ? p6 : (s == 7) ? p7 : p8;
        dstf[e] = loadf(p, mode, local);
    } else {
        int e2 = e - CAN_TOTAL;
        if (e2 >= BW_TOTAL) return;
        int src; const void* p;
        if (e2 < W1T_OFF)      { int n = e2 / TD, k = e2 - n * TD;           p = p2; src = k * NPROJ + n; }
        else if (e2 < W2T_OFF) { int l = e2 - W1T_OFF; int n = l >> 7, k = l & 127; p = p5; src = k * HD + n; }
        else                   { int l = e2 - W2T_OFF; int n = l >> 8, k = l & 255; p = p7; src = k * PD + n; }
        dstb[e2] = (short)f2bf(loadf(p, mode, src));
    }
}

// LN over TD=384 for 16 tokens, then proj = xn @ Wx via MFMA; output bf16.
__global__ __launch_bounds__(256) void ln_proj_mfma(
        const void* __restrict__ x,
        const float* __restrict__ canon,
        const short* __restrict__ wxt,
        const int* __restrict__ flags,
        unsigned short* __restrict__ projb) {
    __shared__ __align__(16) short xnb[TPB_LN][TD + 8];
    const int t = threadIdx.x, wv = t >> 6, lane = t & 63;
    const int tok0 = blockIdx.x * TPB_LN;
    const int xm = flags[2];

    float g[6], bv[6];
    #pragma unroll
    for (int j = 0; j < 6; ++j) {
        g[j]  = canon[CAN_LN_G + lane + 64 * j];
        bv[j] = canon[CAN_LN_B + lane + 64 * j];
    }
    #pragma unroll
    for (int rr = 0; rr < TPB_LN / 4; ++rr) {
        const int r = wv * (TPB_LN / 4) + rr;
        float v[6], s = 0.f, sq = 0.f;
        #pragma unroll
        for (int j = 0; j < 6; ++j) {
            v[j] = loadf(x, xm, (tok0 + r) * TD + lane + 64 * j);
            s += v[j]; sq += v[j] * v[j];
        }
        #pragma unroll
        for (int off = 32; off > 0; off >>= 1) {
            s += __shfl_down(s, off); sq += __shfl_down(sq, off);
        }
        s = __shfl(s, 0); sq = __shfl(sq, 0);
        const float mu = s * (1.f / TD);
        const float var = sq * (1.f / TD) - mu * mu;
        const float rs = rsqrtf(var + 1e-5f);
        #pragma unroll
        for (int j = 0; j < 6; ++j)
            xnb[r][lane + 64 * j] = (short)f2bf((v[j] - mu) * rs * g[j] + bv[j]);
    }
    __syncthreads();

    const int qr = lane >> 4, ln16 = lane & 15;
    const int n0 = wv * 64;
    f32x4 acc[4];
    #pragma unroll
    for (int nt = 0; nt < 4; ++nt) acc[nt] = f32x4{0.f, 0.f, 0.f, 0.f};
    #pragma unroll
    for (int ks = 0; ks < 12; ++ks) {
        const int k0 = ks * 32 + qr * 8;
        bf16x8 a = *(const bf16x8*)&xnb[ln16][k0];
        #pragma unroll
        for (int nt = 0; nt < 4; ++nt) {
            bf16x8 b = *(const bf16x8*)(wxt + (n0 + nt * 16 + ln16) * TD + k0);
            acc[nt] = __builtin_amdgcn_mfma_f32_16x16x32_bf16(a, b, acc[nt], 0, 0, 0);
        }
    }
    #pragma unroll
    for (int nt = 0; nt < 4; ++nt) {
        const int c = n0 + nt * 16 + ln16;
        #pragma unroll
        for (int r = 0; r < 4; ++r)
            projb[(tok0 + qr * 4 + r) * NPROJ + c] = f2bf(acc[nt][r]);
    }
}

// Persistent pipelined pair kernel: 1024 blocks x 8 tiles, prefetch 1 tile ahead.
__global__ __launch_bounds__(256, 4) void pair_kernel(
        const void* __restrict__ pair_rep,
        const void* __restrict__ mask,
        const int*  __restrict__ nbr,
        const void* __restrict__ slot,
        const float* __restrict__ canon,
        const short* __restrict__ w1t,
        const short* __restrict__ w2t,
        const unsigned short* __restrict__ projb,
        const int* __restrict__ flags,
        float* __restrict__ out) {
    __shared__ __align__(16) short znb[RPB][PD + 8];   // 8.5 KB raw-z then LN(z), bf16
    __shared__ __align__(16) short Hb[RPB][HD + 8];    // 16.5 KB relu hidden, bf16
    __shared__ float pmf2[2][RPB];

    const int t = threadIdx.x;
    const int wv = t >> 6, lane = t & 63, qr = lane >> 4, ln16 = lane & 15;
    const int mmode = flags[0], smode = flags[1], prm = flags[3];
    const int pA = wv * 32 + ln16;      // epilogue col, nt=0
    const int pB = pA + 16;             // nt=1

    // prefetch registers (raw, converted only at consume)
    int idxn[8];
    unsigned int prAu[8], prBu[8];
    unsigned short pgAu[8], pgBu[8], x2Au, x2Bu;
    int mIdx = 0;
    unsigned int wmn = 0, wmi = 0, wsl = 0;

    const int tile0 = blockIdx.x * TILES_PER_BLK;

    // ---------- prologue: full prefetch of tile0 ----------
    {
        const int row0 = tile0 * RPB, n = row0 >> 6, k0 = row0 & (KNB - 1);
        #pragma unroll
        for (int j = 0; j < 8; ++j) {
            const int row = (j >> 2) * 16 + qr * 4 + (j & 3);
            idxn[j] = nbr[n * KNB + k0 + row];
        }
        x2Au = projb[n * NPROJ + PD + pA];
        x2Bu = projb[n * NPROJ + PD + pB];
        #pragma unroll
        for (int j = 0; j < 8; ++j) {
            pgAu[j] = projb[idxn[j] * NPROJ + pA];
            pgBu[j] = projb[idxn[j] * NPROJ + pB];
        }
        if (prm) {
            const unsigned short* pr = (const unsigned short*)pair_rep;
            #pragma unroll
            for (int j = 0; j < 8; ++j) {
                const int row = (j >> 2) * 16 + qr * 4 + (j & 3);
                prAu[j] = pr[(row0 + row) * PD + pA];
                prBu[j] = pr[(row0 + row) * PD + pB];
            }
        } else {
            const unsigned int* pr = (const unsigned int*)pair_rep;
            #pragma unroll
            for (int j = 0; j < 8; ++j) {
                const int row = (j >> 2) * 16 + qr * 4 + (j & 3);
                prAu[j] = pr[(row0 + row) * PD + pA];
                prBu[j] = pr[(row0 + row) * PD + pB];
            }
        }
        if (t < RPB) {
            mIdx = nbr[n * KNB + k0 + t];
            wmn = flag_word(mask, mmode, n);
            wmi = flag_word(mask, mmode, mIdx);
            wsl = flag_word(slot, smode, n * KNB + k0 + t);
            pmf2[0][t] = (wmn && wmi && wsl) ? 1.f : 0.f;
        }
    }

    #pragma unroll 1
    for (int i = 0; i < TILES_PER_BLK; ++i) {
        const int tile = tile0 + i;
        const int cur = i & 1, nxt = cur ^ 1;
        const int row0 = tile * RPB;
        const int tn = (i + 1 < TILES_PER_BLK) ? tile + 1 : tile;  // clamp (dup loads unused)
        const int row0n = tn * RPB, nn = row0n >> 6, k0n = row0n & (KNB - 1);

        __syncthreads();  // T: LDS reusable, pmf2[cur] ready

        // ---- phase 2: z = (pair + xp2 + xp1[idx])*pm ; residual in regs, bf16 to znb
        float zcA[8], zcB[8];
        const float x2A = bf2f(x2Au), x2B = bf2f(x2Bu);
        #pragma unroll
        for (int j = 0; j < 8; ++j) {
            const int row = (j >> 2) * 16 + qr * 4 + (j & 3);
            const float pm = pmf2[cur][row];
            const float a = prm ? bf2f((unsigned short)prAu[j]) : __uint_as_float(prAu[j]);
            const float b = prm ? bf2f((unsigned short)prBu[j]) : __uint_as_float(prBu[j]);
            zcA[j] = (a + x2A + bf2f(pgAu[j])) * pm;
            zcB[j] = (b + x2B + bf2f(pgBu[j])) * pm;
            znb[row][pA] = (short)f2bf(zcA[j]);
            znb[row][pB] = (short)f2bf(zcB[j]);
        }

        // issue next-tile index loads (consumed at sync C prefetch)
        #pragma unroll
        for (int j = 0; j < 8; ++j) {
            const int row = (j >> 2) * 16 + qr * 4 + (j & 3);
            idxn[j] = nbr[nn * KNB + k0n + row];
        }
        if (t < RPB) mIdx = nbr[nn * KNB + k0n + t];

        __syncthreads();  // A

        // ---- phase 3: in-place per-row LN on znb (wave owns rows wv*8..+8)
        {
            const float g0 = canon[CAN_T_G + lane], g1 = canon[CAN_T_G + lane + 64];
            const float b0 = canon[CAN_T_B + lane], b1v = canon[CAN_T_B + lane + 64];
            #pragma unroll
            for (int rr = 0; rr < 8; ++rr) {
                const int r = wv * 8 + rr;
                const float a0 = bf2f((unsigned short)znb[r][lane]);
                const float a1 = bf2f((unsigned short)znb[r][lane + 64]);
                float s = a0 + a1, sq = a0 * a0 + a1 * a1;
                #pragma unroll
                for (int off = 32; off > 0; off >>= 1) {
                    s += __shfl_down(s, off); sq += __shfl_down(sq, off);
                }
                s = __shfl(s, 0); sq = __shfl(sq, 0);
                const float mu = s * (1.f / PD);
                const float var = sq * (1.f / PD) - mu * mu;
                const float rs = rsqrtf(var + 1e-5f);
                znb[r][lane]      = (short)f2bf((a0 - mu) * rs * g0 + b0);
                znb[r][lane + 64] = (short)f2bf((a1 - mu) * rs * g1 + b1v);
            }
        }
        __syncthreads();  // B

        // ---- phase 4: H = relu(zn @ W1 + b1)
        {
            const int n0 = wv * 64;
            f32x4 acc1[2][4];
            #pragma unroll
            for (int mt = 0; mt < 2; ++mt)
                #pragma unroll
                for (int nt = 0; nt < 4; ++nt) acc1[mt][nt] = f32x4{0.f, 0.f, 0.f, 0.f};
            #pragma unroll
            for (int ks = 0; ks < 4; ++ks) {
                const int k0 = ks * 32 + qr * 8;
                bf16x8 a0 = *(const bf16x8*)&znb[ln16][k0];
                bf16x8 a1 = *(const bf16x8*)&znb[16 + ln16][k0];
                #pragma unroll
                for (int nt = 0; nt < 4; ++nt) {
                    bf16x8 b = *(const bf16x8*)(w1t + (n0 + nt * 16 + ln16) * PD + k0);
                    acc1[0][nt] = __builtin_amdgcn_mfma_f32_16x16x32_bf16(a0, b, acc1[0][nt], 0, 0, 0);
                    acc1[1][nt] = __builtin_amdgcn_mfma_f32_16x16x32_bf16(a1, b, acc1[1][nt], 0, 0, 0);
                }
            }
            #pragma unroll
            for (int nt = 0; nt < 4; ++nt) {
                const int c = n0 + nt * 16 + ln16;
                const float bb = canon[CAN_B1 + c];
                #pragma unroll
                for (int mt = 0; mt < 2; ++mt)
                    #pragma unroll
                    for (int r = 0; r < 4; ++r) {
                        const float h = acc1[mt][nt][r] + bb;
                        Hb[mt * 16 + qr * 4 + r][c] = (short)f2bf(h > 0.f ? h : 0.f);
                    }
            }
        }
        __syncthreads();  // C

        // ---- issue prefetch for tile tn (hidden behind phase 5)
        x2Au = projb[nn * NPROJ + PD + pA];
        x2Bu = projb[nn * NPROJ + PD + pB];
        #pragma unroll
        for (int j = 0; j < 8; ++j) {
            pgAu[j] = projb[idxn[j] * NPROJ + pA];
            pgBu[j] = projb[idxn[j] * NPROJ + pB];
        }
        if (prm) {
            const unsigned short* pr = (const unsigned short*)pair_rep;
            #pragma unroll
            for (int j = 0; j < 8; ++j) {
                const int row = (j >> 2) * 16 + qr * 4 + (j & 3);
                prAu[j] = pr[(row0n + row) * PD + pA];
                prBu[j] = pr[(row0n + row) * PD + pB];
            }
        } else {
            const unsigned int* pr = (const unsigned int*)pair_rep;
            #pragma unroll
            for (int j = 0; j < 8; ++j) {
                const int row = (j >> 2) * 16 + qr * 4 + (j & 3);
                prAu[j] = pr[(row0n + row) * PD + pA];
                prBu[j] = pr[(row0n + row) * PD + pB];
            }
        }
        if (t < RPB) {
            wmn = flag_word(mask, mmode, nn);
            wmi = flag_word(mask, mmode, mIdx);
            wsl = flag_word(slot, smode, nn * KNB + k0n + t);
        }

        // ---- phase 5: O = H @ W2 + b2; out = z + pm*O
        {
            const int p0w = wv * 32;
            f32x4 acc2[2][2];
            #pragma unroll
            for (int mt = 0; mt < 2; ++mt)
                #pragma unroll
                for (int nt = 0; nt < 2; ++nt) acc2[mt][nt] = f32x4{0.f, 0.f, 0.f, 0.f};
            #pragma unroll
            for (int ks = 0; ks < 8; ++ks) {
                const int k0 = ks * 32 + qr * 8;
                bf16x8 a0 = *(const bf16x8*)&Hb[ln16][k0];
                bf16x8 a1 = *(const bf16x8*)&Hb[16 + ln16][k0];
                #pragma unroll
                for (int nt = 0; nt < 2; ++nt) {
                    bf16x8 b = *(const bf16x8*)(w2t + (p0w + nt * 16 + ln16) * HD + k0);
                    acc2[0][nt] = __builtin_amdgcn_mfma_f32_16x16x32_bf16(a0, b, acc2[0][nt], 0, 0, 0);
                    acc2[1][nt] = __builtin_amdgcn_mfma_f32_16x16x32_bf16(a1, b, acc2[1][nt], 0, 0, 0);
                }
            }
            #pragma unroll
            for (int nt = 0; nt < 2; ++nt) {
                const int p = p0w + nt * 16 + ln16;
                const float bb = canon[CAN_B2 + p];
                #pragma unroll
                for (int mt = 0; mt < 2; ++mt)
                    #pragma unroll
                    for (int r = 0; r < 4; ++r) {
                        const int row = mt * 16 + qr * 4 + r;
                        const float pm = pmf2[cur][row];
                        const float o = (acc2[mt][nt][r] + bb) * pm;
                        const float zres = (nt == 0) ? zcA[mt * 4 + r] : zcB[mt * 4 + r];
                        out[(row0 + row) * PD + p] = zres + o;
                    }
            }
        }
        if (t < RPB) pmf2[nxt][t] = (wmn && wmi && wsl) ? 1.f : 0.f;
    }
}

extern "C" void kernel_launch(void* const* d_in, const int* in_sizes, int n_in,
                              void* d_out, int out_size, void* d_ws, size_t ws_size,
                              hipStream_t stream) {
    const void* x        = d_in[0];
    const void* pair_rep = d_in[1];
    const void* mask     = d_in[2];
    const int*  nbr      = (const int*)d_in[3];
    const void* slot     = d_in[4];
    float* out = (float*)d_out;

    int*   flags = (int*)d_ws;
    float* canon = (float*)((char*)d_ws + 64);
    short* bw    = (short*)((char*)d_ws + BW_OFF);
    const short* wxt = bw + WXT_OFF;
    const short* w1t = bw + W1T_OFF;
    const short* w2t = bw + W2T_OFF;
    unsigned short* projb = (unsigned short*)((char*)d_ws + PROJ_OFF);

    detect_kernel<<<1, 256, 0, stream>>>(x, pair_rep, mask, slot, flags);
    prep_kernel<<<(CAN_TOTAL + BW_TOTAL + 255) / 256, 256, 0, stream>>>(
        d_in[5], d_in[6], d_in[7], d_in[8], d_in[9], d_in[10], d_in[11],
        d_in[12], d_in[13], flags, canon, bw);
    ln_proj_mfma<<<N_TOK / TPB_LN, 256, 0, stream>>>(x, canon, wxt, flags, projb);
    pair_kernel<<<(N_TOK * KNB) / (RPB * TILES_PER_BLK), 256, 0, stream>>>(
        pair_rep, mask, nbr, slot, canon, w1t, w2t, projb, flags, out);
}